// Round 15
// baseline (2977.941 us; speedup 1.0000x reference)
//
#include <hip/hip_runtime.h>
#include <hip/hip_bf16.h>
#include <stdint.h>

typedef __attribute__((ext_vector_type(8))) short short8;
typedef __attribute__((ext_vector_type(4))) float f32x4;
typedef __attribute__((ext_vector_type(4))) unsigned short u16x4;

// ---------- bf16 helpers ----------
__device__ __forceinline__ float bf2f(unsigned short h) {
    union { uint32_t u; float f; } v; v.u = ((uint32_t)h) << 16;
    return v.f;
}
// RNE split (cold paths: weights, epilogues)
__device__ __forceinline__ void split_rne(float f, unsigned short& hi, unsigned short& lo) {
    __hip_bfloat16 h = __float2bfloat16(f);
    union { __hip_bfloat16 b; unsigned short u; } ch; ch.b = h; hi = ch.u;
    float hf = __bfloat162float(h);
    __hip_bfloat16 l = __float2bfloat16(f - hf);
    union { __hip_bfloat16 b; unsigned short u; } cl; cl.b = l; lo = cl.u;
}
// truncation split (hot staging path): ~5 VALU ops, err ~2^-16|f|
__device__ __forceinline__ void splitT(float f, unsigned short& hi, unsigned short& lo) {
    union { float f; uint32_t u; } a; a.f = f;
    hi = (unsigned short)(a.u >> 16);
    union { uint32_t u; float f; } b; b.u = a.u & 0xFFFF0000u;
    union { float f; uint32_t u; } c; c.f = f - b.f;
    lo = (unsigned short)(c.u >> 16);
}

__device__ __forceinline__ void gld_lds16(const void* g, void* s) {
    __builtin_amdgcn_global_load_lds(
        (const __attribute__((address_space(1))) void*)(uintptr_t)g,
        (__attribute__((address_space(3))) void*)(uint32_t)(uintptr_t)s,
        16, 0, 0);
}

__device__ __forceinline__ f32x4 mfma16(short8 a, short8 b, f32x4 c) {
    return __builtin_amdgcn_mfma_f32_16x16x32_bf16(a, b, c, 0, 0, 0);
}

// ---------- kernel: split weights + zero accumulators (merged) ----------
__global__ void prep_weights(const float* __restrict__ W1, const float* __restrict__ W2,
                             const float* __restrict__ W3,
                             unsigned short* __restrict__ w1h, unsigned short* __restrict__ w1l,
                             unsigned short* __restrict__ w2h, unsigned short* __restrict__ w2l,
                             unsigned short* __restrict__ w3h, unsigned short* __restrict__ w3l,
                             float* __restrict__ sums, float* __restrict__ counts, int nverts) {
    int t = blockIdx.x * 256 + threadIdx.x;
    if (t < nverts * 3) sums[t] = 0.0f;
    if (t < nverts)     counts[t] = 0.0f;
    float v; unsigned short *ph, *pl; size_t o;
    if (t < 262144) {                       // W1: (512,512) -> W1T (512,512)
        int k = t >> 9, n = t & 511;
        v = W1[t]; o = (size_t)n * 512 + k; ph = w1h; pl = w1l;
    } else if (t < 524288) {                // W2
        int u = t - 262144; int k = u >> 9, n = u & 511;
        v = W2[u]; o = (size_t)n * 512 + k; ph = w2h; pl = w2l;
    } else if (t < 655360) {                // W3: (512,256) -> W3T (256,512)
        int u = t - 524288; int k = u >> 8, n = u & 255;
        v = W3[u]; o = (size_t)n * 512 + k; ph = w3h; pl = w3l;
    } else return;
    unsigned short hi, lo;
    split_rne(v, hi, lo);
    ph[o] = hi; pl[o] = lo;
}

// ---------- kernel: fallback gather of x rows (chunked path) ----------
__global__ void gather_mean(const float* __restrict__ x, const int* __restrict__ faces,
                            unsigned short* __restrict__ Fhi, unsigned short* __restrict__ Flo,
                            int fbase, int fcount, int mrows) {
    int t = blockIdx.x * 256 + threadIdx.x;
    if (t >= (mrows << 7)) return;
    int r = t >> 7;
    int c = (t & 127) << 2;
    f32x4 m = {0.f, 0.f, 0.f, 0.f};
    if (r < fcount) {
        int f = fbase + r;
        int i0 = faces[3 * f], i1 = faces[3 * f + 1], i2 = faces[3 * f + 2];
        f32x4 a = *(const f32x4*)(x + (size_t)i0 * 512 + c);
        f32x4 b = *(const f32x4*)(x + (size_t)i1 * 512 + c);
        f32x4 d = *(const f32x4*)(x + (size_t)i2 * 512 + c);
        m = (a + b + d) * (1.0f / 3.0f);
    }
    u16x4 hv, lv;
#pragma unroll
    for (int j = 0; j < 4; ++j) {
        unsigned short hi, lo;
        split_rne(m[j], hi, lo);
        hv[j] = hi; lv[j] = lo;
    }
    *(u16x4*)(Fhi + (size_t)r * 512 + c) = hv;
    *(u16x4*)(Flo + (size_t)r * 512 + c) = lv;
}

// ---------- split-bf16x2 GEMM, BK=32, 2-deep counted-vmcnt pipeline (round-3 proven) ----------
// OUT: 0 = bias+relu -> split planes; 1 = raw fp32; 2 = bias+relu -> fp32
template<int OUT>
__global__ __launch_bounds__(256, 2)
void gemm_pipe(const unsigned short* __restrict__ Ahi, const unsigned short* __restrict__ Alo,
               const unsigned short* __restrict__ Bhi, const unsigned short* __restrict__ Blo,
               const float* __restrict__ bias,
               void* __restrict__ Out0, unsigned short* __restrict__ Olo,
               int N, int K, int nt) {
    __shared__ __align__(16) unsigned short sm[2][4][128 * 32];

    const int tid  = threadIdx.x;
    const int lane = tid & 63;
    const int w    = tid >> 6;
    const int wr = w >> 1, wc = w & 1;

    const int nwg  = gridDim.x;
    const int orig = blockIdx.x;
    const int q = nwg >> 3, r8 = nwg & 7;
    const int xcd = orig & 7, idx = orig >> 3;
    const int wg = (xcd < r8 ? xcd * (q + 1) : r8 * (q + 1) + (xcd - r8) * q) + idx;
    const int m0 = (wg / nt) << 7;
    const int n0 = (wg % nt) << 7;

    f32x4 acc[4][4] = {};

    const int s_lo  = w * 64 + lane;
    const int row0  = s_lo >> 2;
    const int c0    = ((s_lo & 3) - ((row0 >> 1) & 3)) & 3;
    const int s_hi  = 256 + s_lo;
    const int row1  = (s_hi >> 2) & 127;
    const int c1    = ((s_hi & 3) - ((row1 >> 1) & 3)) & 3;

    const uint32_t oA0 = (uint32_t)(m0 + row0) * (uint32_t)K + (c0 << 3);
    const uint32_t oA1 = (uint32_t)(m0 + row1) * (uint32_t)K + (c1 << 3);
    const uint32_t oB0 = (uint32_t)(n0 + row0) * (uint32_t)K + (c0 << 3);
    const uint32_t oB1 = (uint32_t)(n0 + row1) * (uint32_t)K + (c1 << 3);

    auto stage = [&](int b, int t) {
        const uint32_t k0 = t << 5;
        gld_lds16(Ahi + oA0 + k0, &sm[b][0][(w * 64) * 8]);
        gld_lds16(Ahi + oA1 + k0, &sm[b][0][(256 + w * 64) * 8]);
        gld_lds16(Alo + oA0 + k0, &sm[b][1][(w * 64) * 8]);
        gld_lds16(Alo + oA1 + k0, &sm[b][1][(256 + w * 64) * 8]);
        gld_lds16(Bhi + oB0 + k0, &sm[b][2][(w * 64) * 8]);
        gld_lds16(Bhi + oB1 + k0, &sm[b][2][(256 + w * 64) * 8]);
        gld_lds16(Blo + oB0 + k0, &sm[b][3][(w * 64) * 8]);
        gld_lds16(Blo + oB1 + k0, &sm[b][3][(256 + w * 64) * 8]);
    };

    const int NT = K >> 5;
    stage(0, 0);
    stage(1, 1);

    const int kc  = lane >> 4;
    const int rbA = (wr << 6) + (lane & 15);
    const int rbB = (wc << 6) + (lane & 15);

    for (int t = 0; t < NT; ++t) {
        const int cur = t & 1;

        if (t + 1 < NT) asm volatile("s_waitcnt vmcnt(8)" ::: "memory");
        else            asm volatile("s_waitcnt vmcnt(0)" ::: "memory");
        __builtin_amdgcn_s_barrier();

        short8 ah[4], al[4], bh[4], bl[4];
#pragma unroll
        for (int m = 0; m < 4; ++m) {
            const int r   = rbA + (m << 4);
            const int off = r * 32 + (((kc + (r >> 1)) & 3) << 3);
            ah[m] = *(const short8*)&sm[cur][0][off];
            al[m] = *(const short8*)&sm[cur][1][off];
        }
#pragma unroll
        for (int n = 0; n < 4; ++n) {
            const int r   = rbB + (n << 4);
            const int off = r * 32 + (((kc + (r >> 1)) & 3) << 3);
            bh[n] = *(const short8*)&sm[cur][2][off];
            bl[n] = *(const short8*)&sm[cur][3][off];
        }
        asm volatile("s_waitcnt lgkmcnt(0)" ::: "memory");
        __builtin_amdgcn_sched_barrier(0);
        __builtin_amdgcn_s_barrier();          // everyone done reading buf[cur]

        if (t + 2 < NT) stage(cur, t + 2);     // refill just-freed buffer, don't wait

        __builtin_amdgcn_s_setprio(1);
#pragma unroll
        for (int m = 0; m < 4; ++m)
#pragma unroll
            for (int n = 0; n < 4; ++n)
                acc[m][n] = mfma16(ah[m], bh[n], acc[m][n]);
#pragma unroll
        for (int m = 0; m < 4; ++m)
#pragma unroll
            for (int n = 0; n < 4; ++n)
                acc[m][n] = mfma16(al[m], bh[n], acc[m][n]);
#pragma unroll
        for (int m = 0; m < 4; ++m)
#pragma unroll
            for (int n = 0; n < 4; ++n)
                acc[m][n] = mfma16(ah[m], bl[n], acc[m][n]);
        __builtin_amdgcn_s_setprio(0);
    }

    // epilogue
#pragma unroll
    for (int n = 0; n < 4; ++n) {
        const int col = n0 + (wc << 6) + (n << 4) + (lane & 15);
        const float bv = (OUT == 1) ? 0.0f : bias[col];
#pragma unroll
        for (int m = 0; m < 4; ++m) {
            const int rbase = m0 + (wr << 6) + (m << 4) + ((lane >> 4) << 2);
#pragma unroll
            for (int j = 0; j < 4; ++j) {
                const size_t o = (size_t)(rbase + j) * N + col;
                if (OUT == 1) {
                    ((float*)Out0)[o] = acc[m][n][j];
                } else if (OUT == 2) {
                    ((float*)Out0)[o] = fmaxf(acc[m][n][j] + bv, 0.0f);
                } else {
                    float v = fmaxf(acc[m][n][j] + bv, 0.0f);
                    unsigned short hi, lo;
                    split_rne(v, hi, lo);
                    ((unsigned short*)Out0)[o] = hi;
                    Olo[o] = lo;
                }
            }
        }
    }
}

// ---------- L1 GEMM: A = x (fp32) fused split via reg-stage; B via gld_lds; out raw fp32 ----------
__global__ __launch_bounds__(256, 2)
void gemm_l1(const float* __restrict__ X,
             const unsigned short* __restrict__ Bhi, const unsigned short* __restrict__ Blo,
             float* __restrict__ Out,
             int N, int K, int nt, int nvalid) {
    __shared__ __align__(16) unsigned short sm[2][4][128 * 32];

    const int tid  = threadIdx.x;
    const int lane = tid & 63;
    const int w    = tid >> 6;
    const int wr = w >> 1, wc = w & 1;

    const int nwg  = gridDim.x;
    const int orig = blockIdx.x;
    const int q = nwg >> 3, r8 = nwg & 7;
    const int xcd = orig & 7, idx = orig >> 3;
    const int wg = (xcd < r8 ? xcd * (q + 1) : r8 * (q + 1) + (xcd - r8) * q) + idx;
    const int m0 = (wg / nt) << 7;
    const int n0 = (wg % nt) << 7;

    f32x4 acc[4][4] = {};

    int adst[2], avalid[2];
    uint32_t xoff[2];
#pragma unroll
    for (int i = 0; i < 2; ++i) {
        const int s   = i * 256 + tid;
        const int row = s >> 2;
        const int c   = s & 3;
        adst[i]   = row * 32 + (((c + (row >> 1)) & 3) << 3);
        avalid[i] = (m0 + row) < nvalid;
        xoff[i]   = (uint32_t)(avalid[i] ? (m0 + row) : 0) * (uint32_t)K + (c << 3);
    }
    const int s_lo  = w * 64 + lane;
    const int row0  = s_lo >> 2;
    const int c0    = ((s_lo & 3) - ((row0 >> 1) & 3)) & 3;
    const int s_hi  = 256 + s_lo;
    const int row1  = (s_hi >> 2) & 127;
    const int c1    = ((s_hi & 3) - ((row1 >> 1) & 3)) & 3;
    const uint32_t oB0 = (uint32_t)(n0 + row0) * (uint32_t)K + (c0 << 3);
    const uint32_t oB1 = (uint32_t)(n0 + row1) * (uint32_t)K + (c1 << 3);

    f32x4 fA[2][2];

    auto issueA = [&](int t) {
        const uint32_t k0 = t << 5;
#pragma unroll
        for (int i = 0; i < 2; ++i) {
            const float* src = X + xoff[i] + k0;
            fA[i][0] = *(const f32x4*)src;
            fA[i][1] = *(const f32x4*)(src + 4);
        }
    };
    auto issueB = [&](int b, int t) {
        const uint32_t k0 = t << 5;
        gld_lds16(Bhi + oB0 + k0, &sm[b][2][(w * 64) * 8]);
        gld_lds16(Bhi + oB1 + k0, &sm[b][2][(256 + w * 64) * 8]);
        gld_lds16(Blo + oB0 + k0, &sm[b][3][(w * 64) * 8]);
        gld_lds16(Blo + oB1 + k0, &sm[b][3][(256 + w * 64) * 8]);
    };
    auto cvtWriteA = [&](int b) {
#pragma unroll
        for (int i = 0; i < 2; ++i) {
            short8 hv, lv;
#pragma unroll
            for (int j = 0; j < 8; ++j) {
                float f = avalid[i] ? fA[i][j >> 2][j & 3] : 0.0f;
                unsigned short hi, lo;
                splitT(f, hi, lo);
                hv[j] = (short)hi;
                lv[j] = (short)lo;
            }
            *(short8*)&sm[b][0][adst[i]] = hv;
            *(short8*)&sm[b][1][adst[i]] = lv;
        }
    };

    const int NT = K >> 5;
    issueA(0); issueB(0, 0);
    asm volatile("s_waitcnt vmcnt(4)" ::: "memory");
    cvtWriteA(0);
    issueA(1); issueB(1, 1);
    asm volatile("s_waitcnt vmcnt(4)" ::: "memory");
    cvtWriteA(1);
    asm volatile("s_waitcnt lgkmcnt(0)" ::: "memory");

    const int kc  = lane >> 4;
    const int rbA = (wr << 6) + (lane & 15);
    const int rbB = (wc << 6) + (lane & 15);

    for (int t = 0; t < NT; ++t) {
        const int cur = t & 1;

        if (t + 1 < NT) asm volatile("s_waitcnt vmcnt(4)" ::: "memory");
        else            asm volatile("s_waitcnt vmcnt(0)" ::: "memory");
        __builtin_amdgcn_s_barrier();

        if (t + 2 < NT) issueA(t + 2);

        short8 ah[4], al[4], bh[4], bl[4];
#pragma unroll
        for (int m = 0; m < 4; ++m) {
            const int r   = rbA + (m << 4);
            const int off = r * 32 + (((kc + (r >> 1)) & 3) << 3);
            ah[m] = *(const short8*)&sm[cur][0][off];
            al[m] = *(const short8*)&sm[cur][1][off];
        }
#pragma unroll
        for (int n = 0; n < 4; ++n) {
            const int r   = rbB + (n << 4);
            const int off = r * 32 + (((kc + (r >> 1)) & 3) << 3);
            bh[n] = *(const short8*)&sm[cur][2][off];
            bl[n] = *(const short8*)&sm[cur][3][off];
        }
        asm volatile("s_waitcnt lgkmcnt(0)" ::: "memory");
        __builtin_amdgcn_sched_barrier(0);
        __builtin_amdgcn_s_barrier();

        if (t + 2 < NT) issueB(cur, t + 2);

        __builtin_amdgcn_s_setprio(1);
#pragma unroll
        for (int m = 0; m < 4; ++m)
#pragma unroll
            for (int n = 0; n < 4; ++n)
                acc[m][n] = mfma16(ah[m], bh[n], acc[m][n]);
#pragma unroll
        for (int m = 0; m < 4; ++m)
#pragma unroll
            for (int n = 0; n < 4; ++n)
                acc[m][n] = mfma16(al[m], bh[n], acc[m][n]);
#pragma unroll
        for (int m = 0; m < 4; ++m)
#pragma unroll
            for (int n = 0; n < 4; ++n)
                acc[m][n] = mfma16(ah[m], bl[n], acc[m][n]);
        __builtin_amdgcn_s_setprio(0);

        if (t + 2 < NT) {
            asm volatile("s_waitcnt vmcnt(4)" ::: "memory");
            cvtWriteA(cur);
        }
    }

#pragma unroll
    for (int n = 0; n < 4; ++n) {
        const int col = n0 + (wc << 6) + (n << 4) + (lane & 15);
#pragma unroll
        for (int m = 0; m < 4; ++m) {
            const int rbase = m0 + (wr << 6) + (m << 4) + ((lane >> 4) << 2);
#pragma unroll
            for (int j = 0; j < 4; ++j)
                Out[(size_t)(rbase + j) * N + col] = acc[m][n][j];
        }
    }
}

// ---------- L2 GEMM, BM=128 x BN=128, 48 KB LDS (A dbuf + B single), 3 blocks/CU ----------
// l2g geometry + l2n single-B schedule. Top-of-t vmcnt(0) drains B(t);
// end-of-t vmcnt(4) drains A(t+2), keeps B(t+1) flying.
__global__ __launch_bounds__(256, 3)
void gemm_l2g48(const float* __restrict__ Y, const int* __restrict__ faces,
                const float* __restrict__ b1,
                const unsigned short* __restrict__ Bhi, const unsigned short* __restrict__ Blo,
                const float* __restrict__ bias2,
                unsigned short* __restrict__ Ohi, unsigned short* __restrict__ Olo,
                int N, int K, int nt, int nvalid) {
    __shared__ __align__(16) unsigned short smA[2][2][128 * 32];   // 32 KB
    __shared__ __align__(16) unsigned short smB[2][128 * 32];      // 16 KB

    const int tid  = threadIdx.x;
    const int lane = tid & 63;
    const int w    = tid >> 6;
    const int wr = w >> 1, wc = w & 1;

    const int nwg  = gridDim.x;
    const int orig = blockIdx.x;
    const int q = nwg >> 3, r8 = nwg & 7;
    const int xcd = orig & 7, idx = orig >> 3;
    const int wg = (xcd < r8 ? xcd * (q + 1) : r8 * (q + 1) + (xcd - r8) * q) + idx;
    const int m0 = (wg / nt) << 7;
    const int n0 = (wg % nt) << 7;

    f32x4 acc[4][4] = {};

    int adst[2], avalid[2];
    uint32_t yoff[2][3];
    const int achk = tid & 3;
#pragma unroll
    for (int i = 0; i < 2; ++i) {
        const int s   = i * 256 + tid;
        const int row = s >> 2;
        adst[i]   = row * 32 + (((achk + (row >> 1)) & 3) << 3);
        const int gf  = m0 + row;
        avalid[i] = gf < nvalid;
        const int gfs = avalid[i] ? gf : 0;
#pragma unroll
        for (int r = 0; r < 3; ++r)
            yoff[i][r] = (uint32_t)faces[3 * gfs + r] * (uint32_t)K;
    }
    const int s_lo  = w * 64 + lane;
    const int row0  = s_lo >> 2;
    const int c0    = ((s_lo & 3) - ((row0 >> 1) & 3)) & 3;
    const int s_hi  = 256 + s_lo;
    const int row1  = (s_hi >> 2) & 127;
    const int c1    = ((s_hi & 3) - ((row1 >> 1) & 3)) & 3;
    const uint32_t oB0 = (uint32_t)(n0 + row0) * (uint32_t)K + (c0 << 3);
    const uint32_t oB1 = (uint32_t)(n0 + row1) * (uint32_t)K + (c1 << 3);

    f32x4 fA[2][3][2];
    f32x4 fb[2];

    auto issueA = [&](int t) {
        const uint32_t koff = (uint32_t)(t << 5) + (achk << 3);
#pragma unroll
        for (int i = 0; i < 2; ++i) {
#pragma unroll
            for (int r = 0; r < 3; ++r) {
                const float* src = Y + yoff[i][r] + koff;
                fA[i][r][0] = *(const f32x4*)src;
                fA[i][r][1] = *(const f32x4*)(src + 4);
            }
        }
        fb[0] = *(const f32x4*)(b1 + koff);
        fb[1] = *(const f32x4*)(b1 + koff + 4);
    };
    auto issueB = [&](int t) {
        const uint32_t k0 = t << 5;
        gld_lds16(Bhi + oB0 + k0, &smB[0][(w * 64) * 8]);
        gld_lds16(Bhi + oB1 + k0, &smB[0][(256 + w * 64) * 8]);
        gld_lds16(Blo + oB0 + k0, &smB[1][(w * 64) * 8]);
        gld_lds16(Blo + oB1 + k0, &smB[1][(256 + w * 64) * 8]);
    };
    auto cvtWriteA = [&](int b) {
        const float third = 1.0f / 3.0f;
#pragma unroll
        for (int i = 0; i < 2; ++i) {
            short8 hv, lv;
#pragma unroll
            for (int j = 0; j < 8; ++j) {
                const int h = j >> 2, e = j & 3;
                float f = 0.0f;
                if (avalid[i]) {
                    f = fmaf(fA[i][0][h][e] + fA[i][1][h][e] + fA[i][2][h][e], third, fb[h][e]);
                    f = fmaxf(f, 0.0f);
                }
                unsigned short hi, lo;
                splitT(f, hi, lo);
                hv[j] = (short)hi;
                lv[j] = (short)lo;
            }
            *(short8*)&smA[b][0][adst[i]] = hv;
            *(short8*)&smA[b][1][adst[i]] = lv;
        }
    };

    const int NT = K >> 5;
    // prologue: A(0)->buf0, B(0)->smB, A(1)->buf1
    issueA(0); issueB(0);                                 // [A(0):12(+2 b1), B(0):4]
    asm volatile("s_waitcnt vmcnt(4)" ::: "memory");      // A(0)+b1 done, B(0) flying
    cvtWriteA(0);
    issueA(1);                                            // [B(0):4 older, A(1):14 newer]
    asm volatile("s_waitcnt vmcnt(0)" ::: "memory");      // all done
    cvtWriteA(1);
    asm volatile("s_waitcnt lgkmcnt(0)" ::: "memory");

    const int kc  = lane >> 4;
    const int rbA = (wr << 6) + (lane & 15);
    const int rbB = (wc << 6) + (lane & 15);

    for (int t = 0; t < NT; ++t) {
        const int cur = t & 1;

        asm volatile("s_waitcnt vmcnt(0)" ::: "memory");   // B(t) complete (this wave)
        __builtin_amdgcn_s_barrier();                      // all waves: A(t)+B(t) ready

        if (t + 2 < NT) issueA(t + 2);                     // early reg gather

        short8 ah[4], al[4], bh[4], bl[4];
#pragma unroll
        for (int m = 0; m < 4; ++m) {
            const int r   = rbA + (m << 4);
            const int off = r * 32 + (((kc + (r >> 1)) & 3) << 3);
            ah[m] = *(const short8*)&smA[cur][0][off];
            al[m] = *(const short8*)&smA[cur][1][off];
        }
#pragma unroll
        for (int n = 0; n < 4; ++n) {
            const int r   = rbB + (n << 4);
            const int off = r * 32 + (((kc + (r >> 1)) & 3) << 3);
            bh[n] = *(const short8*)&smB[0][off];
            bl[n] = *(const short8*)&smB[1][off];
        }
        asm volatile("s_waitcnt lgkmcnt(0)" ::: "memory");
        __builtin_amdgcn_sched_barrier(0);
        __builtin_amdgcn_s_barrier();                      // all waves done reading LDS

        if (t + 1 < NT) issueB(t + 1);                     // overwrite smB

        __builtin_amdgcn_s_setprio(1);
#pragma unroll
        for (int m = 0; m < 4; ++m)
#pragma unroll
            for (int n = 0; n < 4; ++n)
                acc[m][n] = mfma16(ah[m], bh[n], acc[m][n]);
#pragma unroll
        for (int m = 0; m < 4; ++m)
#pragma unroll
            for (int n = 0; n < 4; ++n)
                acc[m][n] = mfma16(al[m], bh[n], acc[m][n]);
#pragma unroll
        for (int m = 0; m < 4; ++m)
#pragma unroll
            for (int n = 0; n < 4; ++n)
                acc[m][n] = mfma16(ah[m], bl[n], acc[m][n]);
        __builtin_amdgcn_s_setprio(0);

        if (t + 2 < NT) {
            // in flight: [A(t+2):14 older, B(t+1):4 newer] -> drain A, keep B flying
            asm volatile("s_waitcnt vmcnt(4)" ::: "memory");
            cvtWriteA(cur);                                // drained by t+1's lgkmcnt(0)
        }
    }

    // epilogue: bias2 + relu + split planes (RNE, cold)
#pragma unroll
    for (int n = 0; n < 4; ++n) {
        const int col = n0 + (wc << 6) + (n << 4) + (lane & 15);
        const float bv = bias2[col];
#pragma unroll
        for (int m = 0; m < 4; ++m) {
            const int rbase = m0 + (wr << 6) + (m << 4) + ((lane >> 4) << 2);
#pragma unroll
            for (int j = 0; j < 4; ++j) {
                const size_t o = (size_t)(rbase + j) * N + col;
                float v = fmaxf(acc[m][n][j] + bv, 0.0f);
                unsigned short hi, lo;
                split_rne(v, hi, lo);
                Ohi[o] = hi;
                Olo[o] = lo;
            }
        }
    }
}

// ---------- Jacobi rotation macro ----------
#define JROT(app, aqq, apq, apz, aqz, vp0, vp1, vp2, vq0, vq1, vq2) do {          \
    float _apq = (apq);                                                            \
    if (fabsf(_apq) > 1e-30f) {                                                    \
        float _tau = ((aqq) - (app)) / (2.0f * _apq);                              \
        float _t = copysignf(1.0f, _tau) / (fabsf(_tau) + sqrtf(1.0f + _tau*_tau));\
        float _c = 1.0f / sqrtf(1.0f + _t*_t);                                     \
        float _s = _t * _c;                                                        \
        (app) = (app) - _t * _apq;                                                 \
        (aqq) = (aqq) + _t * _apq;                                                 \
        (apq) = 0.0f;                                                              \
        float _pz = (apz), _qz = (aqz);                                            \
        (apz) = _c * _pz - _s * _qz;                                               \
        (aqz) = _s * _pz + _c * _qz;                                               \
        float _x;                                                                  \
        _x = (vp0); (vp0) = _c*_x - _s*(vq0); (vq0) = _s*_x + _c*(vq0);            \
        _x = (vp1); (vp1) = _c*_x - _s*(vq1); (vq1) = _s*_x + _c*(vq1);            \
        _x = (vp2); (vp2) = _c*_x - _s*(vq2); (vq2) = _s*_x + _c*(vq2);            \
    }                                                                              \
} while (0)

#define SWAP3(la, lb, x0, y0, z0, x1, y1, z1) do {                \
    float _tm;                                                    \
    _tm = la; la = lb; lb = _tm;                                  \
    _tm = x0; x0 = x1; x1 = _tm;                                  \
    _tm = y0; y0 = y1; y1 = _tm;                                  \
    _tm = z0; z0 = z1; z1 = _tm;                                  \
} while (0)

// ---------- kernel: L4 GEMV (fp32 h3) + procrustes + transform + scatter ----------
__global__ void face_kernel(const float* __restrict__ H3,
                            const float* __restrict__ W4, const float* __restrict__ b4,
                            const float* __restrict__ verts, const int* __restrict__ faces,
                            float* __restrict__ out_tp, float* __restrict__ out_rot,
                            float* __restrict__ sums, float* __restrict__ counts,
                            int fbase, int fcount) {
    __shared__ float sW[256 * 12 + 12];
    for (int i = threadIdx.x; i < 256 * 12 + 12; i += 256)
        sW[i] = (i < 256 * 12) ? W4[i] : b4[i - 256 * 12];
    __syncthreads();

    const int r = blockIdx.x * 256 + threadIdx.x;
    if (r >= fcount) return;
    const int f = fbase + r;

    float o[12];
#pragma unroll
    for (int n = 0; n < 12; ++n) o[n] = sW[3072 + n];
    const f32x4* ph = (const f32x4*)(H3 + (size_t)r * 256);
    for (int kb = 0; kb < 64; ++kb) {
        f32x4 hv = ph[kb];
#pragma unroll
        for (int kk = 0; kk < 4; ++kk) {
            float val = hv[kk];
            const float* wrow = &sW[(kb * 4 + kk) * 12];
#pragma unroll
            for (int n = 0; n < 12; ++n) o[n] = fmaf(val, wrow[n], o[n]);
        }
    }

    const float M00=o[0], M01=o[1], M02=o[2];
    const float M10=o[3], M11=o[4], M12=o[5];
    const float M20=o[6], M21=o[7], M22=o[8];
    const float t0 =o[9], t1 =o[10], t2 =o[11];

    float a00 = M00*M00 + M10*M10 + M20*M20;
    float a11 = M01*M01 + M11*M11 + M21*M21;
    float a22 = M02*M02 + M12*M12 + M22*M22;
    float a01 = M00*M01 + M10*M11 + M20*M21;
    float a02 = M00*M02 + M10*M12 + M20*M22;
    float a12 = M01*M02 + M11*M12 + M21*M22;

    float v00=1.f, v01=0.f, v02=0.f;
    float v10=0.f, v11=1.f, v12=0.f;
    float v20=0.f, v21=0.f, v22=1.f;
#pragma unroll
    for (int sweep = 0; sweep < 5; ++sweep) {
        JROT(a00, a11, a01, a02, a12, v00, v10, v20, v01, v11, v21);
        JROT(a00, a22, a02, a01, a12, v00, v10, v20, v02, v12, v22);
        JROT(a11, a22, a12, a01, a02, v01, v11, v21, v02, v12, v22);
    }
    float l0 = a00, l1 = a11, l2 = a22;
    if (l0 < l1) SWAP3(l0, l1, v00, v10, v20, v01, v11, v21);
    if (l0 < l2) SWAP3(l0, l2, v00, v10, v20, v02, v12, v22);
    if (l1 < l2) SWAP3(l1, l2, v01, v11, v21, v02, v12, v22);

    float b1x = M00*v00 + M01*v10 + M02*v20;
    float b1y = M10*v00 + M11*v10 + M12*v20;
    float b1z = M20*v00 + M21*v10 + M22*v20;
    float b2x = M00*v01 + M01*v11 + M02*v21;
    float b2y = M10*v01 + M11*v11 + M12*v21;
    float b2z = M20*v01 + M21*v11 + M22*v21;

    float n1 = sqrtf(b1x*b1x + b1y*b1y + b1z*b1z);
    float u1x, u1y, u1z;
    if (n1 > 1e-25f) { float in = 1.0f / n1; u1x = b1x*in; u1y = b1y*in; u1z = b1z*in; }
    else             { u1x = 1.f; u1y = 0.f; u1z = 0.f; }

    float dp  = b2x*u1x + b2y*u1y + b2z*u1z;
    float w2x = b2x - dp*u1x, w2y = b2y - dp*u1y, w2z = b2z - dp*u1z;
    float n2  = sqrtf(w2x*w2x + w2y*w2y + w2z*w2z);
    float u2x, u2y, u2z;
    if (n2 > 1e-25f) { float in = 1.0f / n2; u2x = w2x*in; u2y = w2y*in; u2z = w2z*in; }
    else {
        float ex = (fabsf(u1x) < 0.9f) ? 1.f : 0.f;
        float ey = 1.f - ex;
        float cx = -u1z * ey, cy = u1z * ex, cz = u1x * ey - u1y * ex;
        float cn = rsqrtf(cx*cx + cy*cy + cz*cz);
        u2x = cx * cn; u2y = cy * cn; u2z = cz * cn;
    }
    float u3x = u1y*u2z - u1z*u2y;
    float u3y = u1z*u2x - u1x*u2z;
    float u3z = u1x*u2y - u1y*u2x;

    float dv = v00*(v11*v22 - v12*v21) - v01*(v10*v22 - v12*v20) + v02*(v10*v21 - v11*v20);
    if (dv < 0.f) { v02 = -v02; v12 = -v12; v22 = -v22; }

    float R00 = u1x*v00 + u2x*v01 + u3x*v02;
    float R01 = u1x*v10 + u2x*v11 + u3x*v12;
    float R02 = u1x*v20 + u2x*v21 + u3x*v22;
    float R10 = u1y*v00 + u2y*v01 + u3y*v02;
    float R11 = u1y*v10 + u2y*v11 + u3y*v12;
    float R12 = u1y*v20 + u2y*v21 + u3y*v22;
    float R20 = u1z*v00 + u2z*v01 + u3z*v02;
    float R21 = u1z*v10 + u2z*v11 + u3z*v12;
    float R22 = u1z*v20 + u2z*v21 + u3z*v22;

    float* rp = out_rot + (size_t)f * 9;
    rp[0]=R00; rp[1]=R01; rp[2]=R02;
    rp[3]=R10; rp[4]=R11; rp[5]=R12;
    rp[6]=R20; rp[7]=R21; rp[8]=R22;

    float* tp = out_tp + (size_t)f * 9;
    const int idx[3] = { faces[3*f], faces[3*f+1], faces[3*f+2] };
#pragma unroll
    for (int j = 0; j < 3; ++j) {
        const int vi = idx[j];
        float px = verts[3*vi], py = verts[3*vi+1], pz = verts[3*vi+2];
        float q0 = px*R00 + py*R10 + pz*R20 + t0;
        float q1 = px*R01 + py*R11 + pz*R21 + t1;
        float q2 = px*R02 + py*R12 + pz*R22 + t2;
        tp[j*3+0] = q0; tp[j*3+1] = q1; tp[j*3+2] = q2;
        atomicAdd(&sums[(size_t)vi*3+0], q0);
        atomicAdd(&sums[(size_t)vi*3+1], q1);
        atomicAdd(&sums[(size_t)vi*3+2], q2);
        atomicAdd(&counts[vi], 1.0f);
    }
}

// ---------- kernel: features = sums / clip(counts,1) ----------
__global__ void finalize_kernel(float* __restrict__ feats, const float* __restrict__ counts, int nverts) {
    int v = blockIdx.x * 256 + threadIdx.x;
    if (v >= nverts) return;
    float c = fmaxf(counts[v], 1.0f);
    feats[v*3+0] = feats[v*3+0] / c;
    feats[v*3+1] = feats[v*3+1] / c;
    feats[v*3+2] = feats[v*3+2] / c;
}

// ---------- host ----------
extern "C" void kernel_launch(void* const* d_in, const int* in_sizes, int n_in,
                              void* d_out, int out_size, void* d_ws, size_t ws_size,
                              hipStream_t stream) {
    const float* x     = (const float*)d_in[0];
    const float* verts = (const float*)d_in[1];
    const int*   faces = (const int*)d_in[2];
    const float* W1 = (const float*)d_in[3];
    const float* b1 = (const float*)d_in[4];
    const float* W2 = (const float*)d_in[5];
    const float* b2 = (const float*)d_in[6];
    const float* W3 = (const float*)d_in[7];
    const float* b3 = (const float*)d_in[8];
    const float* W4 = (const float*)d_in[9];
    const float* b4 = (const float*)d_in[10];

    const int nverts = in_sizes[1] / 3;
    const int nfaces = in_sizes[2] / 3;

    float* out_feats = (float*)d_out;
    float* out_tp    = out_feats + (size_t)nverts * 3;
    float* out_rot   = out_tp + (size_t)nfaces * 9;

    char* ws = (char*)d_ws;
    size_t cur = 0;
    auto carve = [&](size_t bytes) -> void* {
        void* p = ws + cur;
        cur += (bytes + 255) & ~(size_t)255;
        return p;
    };
    unsigned short* w1h = (unsigned short*)carve(512 * 512 * 2);
    unsigned short* w1l = (unsigned short*)carve(512 * 512 * 2);
    unsigned short* w2h = (unsigned short*)carve(512 * 512 * 2);
    unsigned short* w2l = (unsigned short*)carve(512 * 512 * 2);
    unsigned short* w3h = (unsigned short*)carve(256 * 512 * 2);
    unsigned short* w3l = (unsigned short*)carve(256 * 512 * 2);
    float* counts = (float*)carve((size_t)nverts * 4);

    const long MV = ((long)nverts + 127) & ~127L;   // padded vertex rows
    const long MF = ((long)nfaces + 127) & ~127L;   // padded face rows
    const size_t szY   = (size_t)MV * 512 * 4;      // y fp32
    const size_t szH2w = (size_t)MF * 512 * 2;      // one 512-wide bf16 plane
    const size_t szH3f = (size_t)MF * 256 * 4;      // h3 fp32

    const size_t sR1 = (szY > szH3f) ? szY : szH3f;        // y -> h3 (fp32)
    const size_t sR2 = szH2w;                              // h2h
    const size_t sR3 = szH2w;                              // h2l
    const size_t need = cur + sR1 + sR2 + sR3 + 4 * 256;

    prep_weights<<<(655360 + 255) / 256, 256, 0, stream>>>(W1, W2, W3, w1h, w1l, w2h, w2l, w3h, w3l,
                                                           out_feats, counts, nverts);

    if (ws_size >= need) {
        // ---- main path: vertex-GEMM linearity trick; gather fused into L2 ----
        char* R1 = (char*)carve(sR1);
        char* R2 = (char*)carve(sR2);
        char* R3 = (char*)carve(sR3);
        float*          y   = (float*)R1;
        float*          h3  = (float*)R1;      // aliases y (y dead after L2)
        unsigned short* h2h = (unsigned short*)R2;
        unsigned short* h2l = (unsigned short*)R3;

        // L1 on vertices: y = x @ W1 (fused fp32->split staging; no bias/relu yet)
        gemm_l1<<<(int)(MV / 128) * 4, 256, 0, stream>>>(x, w1h, w1l, y, 512, 512, 4, nverts);

        // L2 with fused gather (48 KB LDS, 3 blocks/CU)
        gemm_l2g48<<<(int)(MF / 128) * 4, 256, 0, stream>>>(y, faces, b1, w2h, w2l, b2,
                                                            h2h, h2l, 512, 512, 4, nfaces);

        // L3: h3 = relu(h2 @ W3 + b3), fp32 out (h3 aliases dead y)
        gemm_pipe<2><<<(int)(MF / 128) * 2, 256, 0, stream>>>(h2h, h2l, w3h, w3l, b3, h3, nullptr, 256, 512, 2);

        face_kernel<<<(nfaces + 255) / 256, 256, 0, stream>>>(h3, W4, b4, verts, faces,
                                                              out_tp, out_rot, out_feats, counts,
                                                              0, nfaces);
    } else {
        // ---- fallback: chunked face-row pipeline ----
        long mpad = MF;
        size_t avail = (ws_size > cur) ? (ws_size - cur) : 0;
        long chp = (long)(avail / 4096);
        chp &= ~127L;
        if (chp > mpad) chp = mpad;
        if (chp < 128) chp = 128;
        unsigned short* bAh = (unsigned short*)carve((size_t)chp * 512 * 2);
        unsigned short* bAl = (unsigned short*)carve((size_t)chp * 512 * 2);
        unsigned short* bBh = (unsigned short*)carve((size_t)chp * 512 * 2);
        unsigned short* bBl = (unsigned short*)carve((size_t)chp * 512 * 2);

        for (long base = 0; base < nfaces; base += chp) {
            long rem = (long)nfaces - base;
            int cnt = (int)((rem < chp) ? rem : chp);
            int mc  = (cnt + 127) & ~127;

            gather_mean<<<mc / 2, 256, 0, stream>>>(x, faces, bAh, bAl, (int)base, cnt, mc);
            gemm_pipe<0><<<(mc / 128) * 4, 256, 0, stream>>>(bAh, bAl, w1h, w1l, b1, bBh, bBl, 512, 512, 4);
            gemm_pipe<0><<<(mc / 128) * 4, 256, 0, stream>>>(bBh, bBl, w2h, w2l, b2, bAh, bAl, 512, 512, 4);
            gemm_pipe<2><<<(mc / 128) * 2, 256, 0, stream>>>(bAh, bAl, w3h, w3l, b3, (float*)bBh, nullptr, 256, 512, 2);
            face_kernel<<<(cnt + 255) / 256, 256, 0, stream>>>((float*)bBh, W4, b4, verts, faces,
                                                               out_tp, out_rot, out_feats, counts,
                                                               (int)base, cnt);
        }
    }

    finalize_kernel<<<(nverts + 255) / 256, 256, 0, stream>>>(out_feats, counts, nverts);
}

// Round 16
// 1151.463 us; speedup vs baseline: 2.5862x; 2.5862x over previous
//
#include <hip/hip_runtime.h>
#include <hip/hip_bf16.h>
#include <stdint.h>

typedef __attribute__((ext_vector_type(8))) short short8;
typedef __attribute__((ext_vector_type(4))) float f32x4;
typedef __attribute__((ext_vector_type(4))) unsigned short u16x4;

// ---------- bf16 helpers ----------
__device__ __forceinline__ float bf2f(unsigned short h) {
    union { uint32_t u; float f; } v; v.u = ((uint32_t)h) << 16;
    return v.f;
}
// RNE split (cold paths: weights, epilogues)
__device__ __forceinline__ void split_rne(float f, unsigned short& hi, unsigned short& lo) {
    __hip_bfloat16 h = __float2bfloat16(f);
    union { __hip_bfloat16 b; unsigned short u; } ch; ch.b = h; hi = ch.u;
    float hf = __bfloat162float(h);
    __hip_bfloat16 l = __float2bfloat16(f - hf);
    union { __hip_bfloat16 b; unsigned short u; } cl; cl.b = l; lo = cl.u;
}
// truncation split (hot staging path): ~5 VALU ops, err ~2^-16|f|
__device__ __forceinline__ void splitT(float f, unsigned short& hi, unsigned short& lo) {
    union { float f; uint32_t u; } a; a.f = f;
    hi = (unsigned short)(a.u >> 16);
    union { uint32_t u; float f; } b; b.u = a.u & 0xFFFF0000u;
    union { float f; uint32_t u; } c; c.f = f - b.f;
    lo = (unsigned short)(c.u >> 16);
}

__device__ __forceinline__ void gld_lds16(const void* g, void* s) {
    __builtin_amdgcn_global_load_lds(
        (const __attribute__((address_space(1))) void*)(uintptr_t)g,
        (__attribute__((address_space(3))) void*)(uint32_t)(uintptr_t)s,
        16, 0, 0);
}

__device__ __forceinline__ f32x4 mfma16(short8 a, short8 b, f32x4 c) {
    return __builtin_amdgcn_mfma_f32_16x16x32_bf16(a, b, c, 0, 0, 0);
}

// ---------- kernel: split weights + zero accumulators (merged) ----------
__global__ void prep_weights(const float* __restrict__ W1, const float* __restrict__ W2,
                             const float* __restrict__ W3,
                             unsigned short* __restrict__ w1h, unsigned short* __restrict__ w1l,
                             unsigned short* __restrict__ w2h, unsigned short* __restrict__ w2l,
                             unsigned short* __restrict__ w3h, unsigned short* __restrict__ w3l,
                             float* __restrict__ sums, float* __restrict__ counts, int nverts) {
    int t = blockIdx.x * 256 + threadIdx.x;
    if (t < nverts * 3) sums[t] = 0.0f;
    if (t < nverts)     counts[t] = 0.0f;
    float v; unsigned short *ph, *pl; size_t o;
    if (t < 262144) {                       // W1: (512,512) -> W1T (512,512)
        int k = t >> 9, n = t & 511;
        v = W1[t]; o = (size_t)n * 512 + k; ph = w1h; pl = w1l;
    } else if (t < 524288) {                // W2
        int u = t - 262144; int k = u >> 9, n = u & 511;
        v = W2[u]; o = (size_t)n * 512 + k; ph = w2h; pl = w2l;
    } else if (t < 655360) {                // W3: (512,256) -> W3T (256,512)
        int u = t - 524288; int k = u >> 8, n = u & 255;
        v = W3[u]; o = (size_t)n * 512 + k; ph = w3h; pl = w3l;
    } else return;
    unsigned short hi, lo;
    split_rne(v, hi, lo);
    ph[o] = hi; pl[o] = lo;
}

// ---------- kernel: fallback gather of x rows (chunked path) ----------
__global__ void gather_mean(const float* __restrict__ x, const int* __restrict__ faces,
                            unsigned short* __restrict__ Fhi, unsigned short* __restrict__ Flo,
                            int fbase, int fcount, int mrows) {
    int t = blockIdx.x * 256 + threadIdx.x;
    if (t >= (mrows << 7)) return;
    int r = t >> 7;
    int c = (t & 127) << 2;
    f32x4 m = {0.f, 0.f, 0.f, 0.f};
    if (r < fcount) {
        int f = fbase + r;
        int i0 = faces[3 * f], i1 = faces[3 * f + 1], i2 = faces[3 * f + 2];
        f32x4 a = *(const f32x4*)(x + (size_t)i0 * 512 + c);
        f32x4 b = *(const f32x4*)(x + (size_t)i1 * 512 + c);
        f32x4 d = *(const f32x4*)(x + (size_t)i2 * 512 + c);
        m = (a + b + d) * (1.0f / 3.0f);
    }
    u16x4 hv, lv;
#pragma unroll
    for (int j = 0; j < 4; ++j) {
        unsigned short hi, lo;
        split_rne(m[j], hi, lo);
        hv[j] = hi; lv[j] = lo;
    }
    *(u16x4*)(Fhi + (size_t)r * 512 + c) = hv;
    *(u16x4*)(Flo + (size_t)r * 512 + c) = lv;
}

// ---------- split-bf16x2 GEMM, BK=32, 2-deep counted-vmcnt pipeline (round-3 proven) ----------
// OUT: 0 = bias+relu -> split planes; 1 = raw fp32; 2 = bias+relu -> fp32
template<int OUT>
__global__ __launch_bounds__(256, 2)
void gemm_pipe(const unsigned short* __restrict__ Ahi, const unsigned short* __restrict__ Alo,
               const unsigned short* __restrict__ Bhi, const unsigned short* __restrict__ Blo,
               const float* __restrict__ bias,
               void* __restrict__ Out0, unsigned short* __restrict__ Olo,
               int N, int K, int nt) {
    __shared__ __align__(16) unsigned short sm[2][4][128 * 32];

    const int tid  = threadIdx.x;
    const int lane = tid & 63;
    const int w    = tid >> 6;
    const int wr = w >> 1, wc = w & 1;

    const int nwg  = gridDim.x;
    const int orig = blockIdx.x;
    const int q = nwg >> 3, r8 = nwg & 7;
    const int xcd = orig & 7, idx = orig >> 3;
    const int wg = (xcd < r8 ? xcd * (q + 1) : r8 * (q + 1) + (xcd - r8) * q) + idx;
    const int m0 = (wg / nt) << 7;
    const int n0 = (wg % nt) << 7;

    f32x4 acc[4][4] = {};

    const int s_lo  = w * 64 + lane;
    const int row0  = s_lo >> 2;
    const int c0    = ((s_lo & 3) - ((row0 >> 1) & 3)) & 3;
    const int s_hi  = 256 + s_lo;
    const int row1  = (s_hi >> 2) & 127;
    const int c1    = ((s_hi & 3) - ((row1 >> 1) & 3)) & 3;

    const uint32_t oA0 = (uint32_t)(m0 + row0) * (uint32_t)K + (c0 << 3);
    const uint32_t oA1 = (uint32_t)(m0 + row1) * (uint32_t)K + (c1 << 3);
    const uint32_t oB0 = (uint32_t)(n0 + row0) * (uint32_t)K + (c0 << 3);
    const uint32_t oB1 = (uint32_t)(n0 + row1) * (uint32_t)K + (c1 << 3);

    auto stage = [&](int b, int t) {
        const uint32_t k0 = t << 5;
        gld_lds16(Ahi + oA0 + k0, &sm[b][0][(w * 64) * 8]);
        gld_lds16(Ahi + oA1 + k0, &sm[b][0][(256 + w * 64) * 8]);
        gld_lds16(Alo + oA0 + k0, &sm[b][1][(w * 64) * 8]);
        gld_lds16(Alo + oA1 + k0, &sm[b][1][(256 + w * 64) * 8]);
        gld_lds16(Bhi + oB0 + k0, &sm[b][2][(w * 64) * 8]);
        gld_lds16(Bhi + oB1 + k0, &sm[b][2][(256 + w * 64) * 8]);
        gld_lds16(Blo + oB0 + k0, &sm[b][3][(w * 64) * 8]);
        gld_lds16(Blo + oB1 + k0, &sm[b][3][(256 + w * 64) * 8]);
    };

    const int NT = K >> 5;
    stage(0, 0);
    stage(1, 1);

    const int kc  = lane >> 4;
    const int rbA = (wr << 6) + (lane & 15);
    const int rbB = (wc << 6) + (lane & 15);

    for (int t = 0; t < NT; ++t) {
        const int cur = t & 1;

        if (t + 1 < NT) asm volatile("s_waitcnt vmcnt(8)" ::: "memory");
        else            asm volatile("s_waitcnt vmcnt(0)" ::: "memory");
        __builtin_amdgcn_s_barrier();

        short8 ah[4], al[4], bh[4], bl[4];
#pragma unroll
        for (int m = 0; m < 4; ++m) {
            const int r   = rbA + (m << 4);
            const int off = r * 32 + (((kc + (r >> 1)) & 3) << 3);
            ah[m] = *(const short8*)&sm[cur][0][off];
            al[m] = *(const short8*)&sm[cur][1][off];
        }
#pragma unroll
        for (int n = 0; n < 4; ++n) {
            const int r   = rbB + (n << 4);
            const int off = r * 32 + (((kc + (r >> 1)) & 3) << 3);
            bh[n] = *(const short8*)&sm[cur][2][off];
            bl[n] = *(const short8*)&sm[cur][3][off];
        }
        asm volatile("s_waitcnt lgkmcnt(0)" ::: "memory");
        __builtin_amdgcn_sched_barrier(0);
        __builtin_amdgcn_s_barrier();          // everyone done reading buf[cur]

        if (t + 2 < NT) stage(cur, t + 2);     // refill just-freed buffer, don't wait

        __builtin_amdgcn_s_setprio(1);
#pragma unroll
        for (int m = 0; m < 4; ++m)
#pragma unroll
            for (int n = 0; n < 4; ++n)
                acc[m][n] = mfma16(ah[m], bh[n], acc[m][n]);
#pragma unroll
        for (int m = 0; m < 4; ++m)
#pragma unroll
            for (int n = 0; n < 4; ++n)
                acc[m][n] = mfma16(al[m], bh[n], acc[m][n]);
#pragma unroll
        for (int m = 0; m < 4; ++m)
#pragma unroll
            for (int n = 0; n < 4; ++n)
                acc[m][n] = mfma16(ah[m], bl[n], acc[m][n]);
        __builtin_amdgcn_s_setprio(0);
    }

    // epilogue
#pragma unroll
    for (int n = 0; n < 4; ++n) {
        const int col = n0 + (wc << 6) + (n << 4) + (lane & 15);
        const float bv = (OUT == 1) ? 0.0f : bias[col];
#pragma unroll
        for (int m = 0; m < 4; ++m) {
            const int rbase = m0 + (wr << 6) + (m << 4) + ((lane >> 4) << 2);
#pragma unroll
            for (int j = 0; j < 4; ++j) {
                const size_t o = (size_t)(rbase + j) * N + col;
                if (OUT == 1) {
                    ((float*)Out0)[o] = acc[m][n][j];
                } else if (OUT == 2) {
                    ((float*)Out0)[o] = fmaxf(acc[m][n][j] + bv, 0.0f);
                } else {
                    float v = fmaxf(acc[m][n][j] + bv, 0.0f);
                    unsigned short hi, lo;
                    split_rne(v, hi, lo);
                    ((unsigned short*)Out0)[o] = hi;
                    Olo[o] = lo;
                }
            }
        }
    }
}

// ---------- L1 GEMM: A = x (fp32) fused split via reg-stage; B via gld_lds; out raw fp32 ----------
__global__ __launch_bounds__(256, 2)
void gemm_l1(const float* __restrict__ X,
             const unsigned short* __restrict__ Bhi, const unsigned short* __restrict__ Blo,
             float* __restrict__ Out,
             int N, int K, int nt, int nvalid) {
    __shared__ __align__(16) unsigned short sm[2][4][128 * 32];

    const int tid  = threadIdx.x;
    const int lane = tid & 63;
    const int w    = tid >> 6;
    const int wr = w >> 1, wc = w & 1;

    const int nwg  = gridDim.x;
    const int orig = blockIdx.x;
    const int q = nwg >> 3, r8 = nwg & 7;
    const int xcd = orig & 7, idx = orig >> 3;
    const int wg = (xcd < r8 ? xcd * (q + 1) : r8 * (q + 1) + (xcd - r8) * q) + idx;
    const int m0 = (wg / nt) << 7;
    const int n0 = (wg % nt) << 7;

    f32x4 acc[4][4] = {};

    int adst[2], avalid[2];
    uint32_t xoff[2];
#pragma unroll
    for (int i = 0; i < 2; ++i) {
        const int s   = i * 256 + tid;
        const int row = s >> 2;
        const int c   = s & 3;
        adst[i]   = row * 32 + (((c + (row >> 1)) & 3) << 3);
        avalid[i] = (m0 + row) < nvalid;
        xoff[i]   = (uint32_t)(avalid[i] ? (m0 + row) : 0) * (uint32_t)K + (c << 3);
    }
    const int s_lo  = w * 64 + lane;
    const int row0  = s_lo >> 2;
    const int c0    = ((s_lo & 3) - ((row0 >> 1) & 3)) & 3;
    const int s_hi  = 256 + s_lo;
    const int row1  = (s_hi >> 2) & 127;
    const int c1    = ((s_hi & 3) - ((row1 >> 1) & 3)) & 3;
    const uint32_t oB0 = (uint32_t)(n0 + row0) * (uint32_t)K + (c0 << 3);
    const uint32_t oB1 = (uint32_t)(n0 + row1) * (uint32_t)K + (c1 << 3);

    f32x4 fA[2][2];

    auto issueA = [&](int t) {
        const uint32_t k0 = t << 5;
#pragma unroll
        for (int i = 0; i < 2; ++i) {
            const float* src = X + xoff[i] + k0;
            fA[i][0] = *(const f32x4*)src;
            fA[i][1] = *(const f32x4*)(src + 4);
        }
    };
    auto issueB = [&](int b, int t) {
        const uint32_t k0 = t << 5;
        gld_lds16(Bhi + oB0 + k0, &sm[b][2][(w * 64) * 8]);
        gld_lds16(Bhi + oB1 + k0, &sm[b][2][(256 + w * 64) * 8]);
        gld_lds16(Blo + oB0 + k0, &sm[b][3][(w * 64) * 8]);
        gld_lds16(Blo + oB1 + k0, &sm[b][3][(256 + w * 64) * 8]);
    };
    auto cvtWriteA = [&](int b) {
#pragma unroll
        for (int i = 0; i < 2; ++i) {
            short8 hv, lv;
#pragma unroll
            for (int j = 0; j < 8; ++j) {
                float f = avalid[i] ? fA[i][j >> 2][j & 3] : 0.0f;
                unsigned short hi, lo;
                splitT(f, hi, lo);
                hv[j] = (short)hi;
                lv[j] = (short)lo;
            }
            *(short8*)&sm[b][0][adst[i]] = hv;
            *(short8*)&sm[b][1][adst[i]] = lv;
        }
    };

    const int NT = K >> 5;
    issueA(0); issueB(0, 0);
    asm volatile("s_waitcnt vmcnt(4)" ::: "memory");
    cvtWriteA(0);
    issueA(1); issueB(1, 1);
    asm volatile("s_waitcnt vmcnt(4)" ::: "memory");
    cvtWriteA(1);
    asm volatile("s_waitcnt lgkmcnt(0)" ::: "memory");

    const int kc  = lane >> 4;
    const int rbA = (wr << 6) + (lane & 15);
    const int rbB = (wc << 6) + (lane & 15);

    for (int t = 0; t < NT; ++t) {
        const int cur = t & 1;

        if (t + 1 < NT) asm volatile("s_waitcnt vmcnt(4)" ::: "memory");
        else            asm volatile("s_waitcnt vmcnt(0)" ::: "memory");
        __builtin_amdgcn_s_barrier();

        if (t + 2 < NT) issueA(t + 2);

        short8 ah[4], al[4], bh[4], bl[4];
#pragma unroll
        for (int m = 0; m < 4; ++m) {
            const int r   = rbA + (m << 4);
            const int off = r * 32 + (((kc + (r >> 1)) & 3) << 3);
            ah[m] = *(const short8*)&sm[cur][0][off];
            al[m] = *(const short8*)&sm[cur][1][off];
        }
#pragma unroll
        for (int n = 0; n < 4; ++n) {
            const int r   = rbB + (n << 4);
            const int off = r * 32 + (((kc + (r >> 1)) & 3) << 3);
            bh[n] = *(const short8*)&sm[cur][2][off];
            bl[n] = *(const short8*)&sm[cur][3][off];
        }
        asm volatile("s_waitcnt lgkmcnt(0)" ::: "memory");
        __builtin_amdgcn_sched_barrier(0);
        __builtin_amdgcn_s_barrier();

        if (t + 2 < NT) issueB(cur, t + 2);

        __builtin_amdgcn_s_setprio(1);
#pragma unroll
        for (int m = 0; m < 4; ++m)
#pragma unroll
            for (int n = 0; n < 4; ++n)
                acc[m][n] = mfma16(ah[m], bh[n], acc[m][n]);
#pragma unroll
        for (int m = 0; m < 4; ++m)
#pragma unroll
            for (int n = 0; n < 4; ++n)
                acc[m][n] = mfma16(al[m], bh[n], acc[m][n]);
#pragma unroll
        for (int m = 0; m < 4; ++m)
#pragma unroll
            for (int n = 0; n < 4; ++n)
                acc[m][n] = mfma16(ah[m], bl[n], acc[m][n]);
        __builtin_amdgcn_s_setprio(0);

        if (t + 2 < NT) {
            asm volatile("s_waitcnt vmcnt(4)" ::: "memory");
            cvtWriteA(cur);
        }
    }

#pragma unroll
    for (int n = 0; n < 4; ++n) {
        const int col = n0 + (wc << 6) + (n << 4) + (lane & 15);
#pragma unroll
        for (int m = 0; m < 4; ++m) {
            const int rbase = m0 + (wr << 6) + (m << 4) + ((lane >> 4) << 2);
#pragma unroll
            for (int j = 0; j < 4; ++j)
                Out[(size_t)(rbase + j) * N + col] = acc[m][n][j];
        }
    }
}

// ---------- L2 GEMM, BM=128 x BN=128, 48 KB LDS (A dbuf + B single) ----------
// Round-15 schedule, but __launch_bounds__(256,2): compiler allocates ~112 VGPR
// (no spill); occupancy becomes LDS-limited at 3 blocks/CU (160/48).
__global__ __launch_bounds__(256, 2)
void gemm_l2g48(const float* __restrict__ Y, const int* __restrict__ faces,
                const float* __restrict__ b1,
                const unsigned short* __restrict__ Bhi, const unsigned short* __restrict__ Blo,
                const float* __restrict__ bias2,
                unsigned short* __restrict__ Ohi, unsigned short* __restrict__ Olo,
                int N, int K, int nt, int nvalid) {
    __shared__ __align__(16) unsigned short smA[2][2][128 * 32];   // 32 KB
    __shared__ __align__(16) unsigned short smB[2][128 * 32];      // 16 KB

    const int tid  = threadIdx.x;
    const int lane = tid & 63;
    const int w    = tid >> 6;
    const int wr = w >> 1, wc = w & 1;

    const int nwg  = gridDim.x;
    const int orig = blockIdx.x;
    const int q = nwg >> 3, r8 = nwg & 7;
    const int xcd = orig & 7, idx = orig >> 3;
    const int wg = (xcd < r8 ? xcd * (q + 1) : r8 * (q + 1) + (xcd - r8) * q) + idx;
    const int m0 = (wg / nt) << 7;
    const int n0 = (wg % nt) << 7;

    f32x4 acc[4][4] = {};

    int adst[2], avalid[2];
    uint32_t yoff[2][3];
    const int achk = tid & 3;
#pragma unroll
    for (int i = 0; i < 2; ++i) {
        const int s   = i * 256 + tid;
        const int row = s >> 2;
        adst[i]   = row * 32 + (((achk + (row >> 1)) & 3) << 3);
        const int gf  = m0 + row;
        avalid[i] = gf < nvalid;
        const int gfs = avalid[i] ? gf : 0;
#pragma unroll
        for (int r = 0; r < 3; ++r)
            yoff[i][r] = (uint32_t)faces[3 * gfs + r] * (uint32_t)K;
    }
    const int s_lo  = w * 64 + lane;
    const int row0  = s_lo >> 2;
    const int c0    = ((s_lo & 3) - ((row0 >> 1) & 3)) & 3;
    const int s_hi  = 256 + s_lo;
    const int row1  = (s_hi >> 2) & 127;
    const int c1    = ((s_hi & 3) - ((row1 >> 1) & 3)) & 3;
    const uint32_t oB0 = (uint32_t)(n0 + row0) * (uint32_t)K + (c0 << 3);
    const uint32_t oB1 = (uint32_t)(n0 + row1) * (uint32_t)K + (c1 << 3);

    f32x4 fA[2][3][2];
    f32x4 fb[2];

    auto issueA = [&](int t) {
        const uint32_t koff = (uint32_t)(t << 5) + (achk << 3);
#pragma unroll
        for (int i = 0; i < 2; ++i) {
#pragma unroll
            for (int r = 0; r < 3; ++r) {
                const float* src = Y + yoff[i][r] + koff;
                fA[i][r][0] = *(const f32x4*)src;
                fA[i][r][1] = *(const f32x4*)(src + 4);
            }
        }
        fb[0] = *(const f32x4*)(b1 + koff);
        fb[1] = *(const f32x4*)(b1 + koff + 4);
    };
    auto issueB = [&](int t) {
        const uint32_t k0 = t << 5;
        gld_lds16(Bhi + oB0 + k0, &smB[0][(w * 64) * 8]);
        gld_lds16(Bhi + oB1 + k0, &smB[0][(256 + w * 64) * 8]);
        gld_lds16(Blo + oB0 + k0, &smB[1][(w * 64) * 8]);
        gld_lds16(Blo + oB1 + k0, &smB[1][(256 + w * 64) * 8]);
    };
    auto cvtWriteA = [&](int b) {
        const float third = 1.0f / 3.0f;
#pragma unroll
        for (int i = 0; i < 2; ++i) {
            short8 hv, lv;
#pragma unroll
            for (int j = 0; j < 8; ++j) {
                const int h = j >> 2, e = j & 3;
                float f = 0.0f;
                if (avalid[i]) {
                    f = fmaf(fA[i][0][h][e] + fA[i][1][h][e] + fA[i][2][h][e], third, fb[h][e]);
                    f = fmaxf(f, 0.0f);
                }
                unsigned short hi, lo;
                splitT(f, hi, lo);
                hv[j] = (short)hi;
                lv[j] = (short)lo;
            }
            *(short8*)&smA[b][0][adst[i]] = hv;
            *(short8*)&smA[b][1][adst[i]] = lv;
        }
    };

    const int NT = K >> 5;
    // prologue: A(0)->buf0, B(0)->smB, A(1)->buf1
    issueA(0); issueB(0);                                 // [A(0):12(+2 b1), B(0):4]
    asm volatile("s_waitcnt vmcnt(4)" ::: "memory");      // A(0)+b1 done, B(0) flying
    cvtWriteA(0);
    issueA(1);                                            // [B(0):4 older, A(1):14 newer]
    asm volatile("s_waitcnt vmcnt(0)" ::: "memory");      // all done
    cvtWriteA(1);
    asm volatile("s_waitcnt lgkmcnt(0)" ::: "memory");

    const int kc  = lane >> 4;
    const int rbA = (wr << 6) + (lane & 15);
    const int rbB = (wc << 6) + (lane & 15);

    for (int t = 0; t < NT; ++t) {
        const int cur = t & 1;

        asm volatile("s_waitcnt vmcnt(0)" ::: "memory");   // B(t) complete (this wave)
        __builtin_amdgcn_s_barrier();                      // all waves: A(t)+B(t) ready

        if (t + 2 < NT) issueA(t + 2);                     // early reg gather

        short8 ah[4], al[4], bh[4], bl[4];
#pragma unroll
        for (int m = 0; m < 4; ++m) {
            const int r   = rbA + (m << 4);
            const int off = r * 32 + (((kc + (r >> 1)) & 3) << 3);
            ah[m] = *(const short8*)&smA[cur][0][off];
            al[m] = *(const short8*)&smA[cur][1][off];
        }
#pragma unroll
        for (int n = 0; n < 4; ++n) {
            const int r   = rbB + (n << 4);
            const int off = r * 32 + (((kc + (r >> 1)) & 3) << 3);
            bh[n] = *(const short8*)&smB[0][off];
            bl[n] = *(const short8*)&smB[1][off];
        }
        asm volatile("s_waitcnt lgkmcnt(0)" ::: "memory");
        __builtin_amdgcn_sched_barrier(0);
        __builtin_amdgcn_s_barrier();                      // all waves done reading LDS

        if (t + 1 < NT) issueB(t + 1);                     // overwrite smB

        __builtin_amdgcn_s_setprio(1);
#pragma unroll
        for (int m = 0; m < 4; ++m)
#pragma unroll
            for (int n = 0; n < 4; ++n)
                acc[m][n] = mfma16(ah[m], bh[n], acc[m][n]);
#pragma unroll
        for (int m = 0; m < 4; ++m)
#pragma unroll
            for (int n = 0; n < 4; ++n)
                acc[m][n] = mfma16(al[m], bh[n], acc[m][n]);
#pragma unroll
        for (int m = 0; m < 4; ++m)
#pragma unroll
            for (int n = 0; n < 4; ++n)
                acc[m][n] = mfma16(ah[m], bl[n], acc[m][n]);
        __builtin_amdgcn_s_setprio(0);

        if (t + 2 < NT) {
            // in flight: [A(t+2):14 older, B(t+1):4 newer] -> drain A, keep B flying
            asm volatile("s_waitcnt vmcnt(4)" ::: "memory");
            cvtWriteA(cur);                                // drained by t+1's lgkmcnt(0)
        }
    }

    // epilogue: bias2 + relu + split planes (RNE, cold)
#pragma unroll
    for (int n = 0; n < 4; ++n) {
        const int col = n0 + (wc << 6) + (n << 4) + (lane & 15);
        const float bv = bias2[col];
#pragma unroll
        for (int m = 0; m < 4; ++m) {
            const int rbase = m0 + (wr << 6) + (m << 4) + ((lane >> 4) << 2);
#pragma unroll
            for (int j = 0; j < 4; ++j) {
                const size_t o = (size_t)(rbase + j) * N + col;
                float v = fmaxf(acc[m][n][j] + bv, 0.0f);
                unsigned short hi, lo;
                split_rne(v, hi, lo);
                Ohi[o] = hi;
                Olo[o] = lo;
            }
        }
    }
}

// ---------- Jacobi rotation macro ----------
#define JROT(app, aqq, apq, apz, aqz, vp0, vp1, vp2, vq0, vq1, vq2) do {          \
    float _apq = (apq);                                                            \
    if (fabsf(_apq) > 1e-30f) {                                                    \
        float _tau = ((aqq) - (app)) / (2.0f * _apq);                              \
        float _t = copysignf(1.0f, _tau) / (fabsf(_tau) + sqrtf(1.0f + _tau*_tau));\
        float _c = 1.0f / sqrtf(1.0f + _t*_t);                                     \
        float _s = _t * _c;                                                        \
        (app) = (app) - _t * _apq;                                                 \
        (aqq) = (aqq) + _t * _apq;                                                 \
        (apq) = 0.0f;                                                              \
        float _pz = (apz), _qz = (aqz);                                            \
        (apz) = _c * _pz - _s * _qz;                                               \
        (aqz) = _s * _pz + _c * _qz;                                               \
        float _x;                                                                  \
        _x = (vp0); (vp0) = _c*_x - _s*(vq0); (vq0) = _s*_x + _c*(vq0);            \
        _x = (vp1); (vp1) = _c*_x - _s*(vq1); (vq1) = _s*_x + _c*(vq1);            \
        _x = (vp2); (vp2) = _c*_x - _s*(vq2); (vq2) = _s*_x + _c*(vq2);            \
    }                                                                              \
} while (0)

#define SWAP3(la, lb, x0, y0, z0, x1, y1, z1) do {                \
    float _tm;                                                    \
    _tm = la; la = lb; lb = _tm;                                  \
    _tm = x0; x0 = x1; x1 = _tm;                                  \
    _tm = y0; y0 = y1; y1 = _tm;                                  \
    _tm = z0; z0 = z1; z1 = _tm;                                  \
} while (0)

// ---------- kernel: L4 GEMV (fp32 h3) + procrustes + transform + scatter ----------
__global__ void face_kernel(const float* __restrict__ H3,
                            const float* __restrict__ W4, const float* __restrict__ b4,
                            const float* __restrict__ verts, const int* __restrict__ faces,
                            float* __restrict__ out_tp, float* __restrict__ out_rot,
                            float* __restrict__ sums, float* __restrict__ counts,
                            int fbase, int fcount) {
    __shared__ float sW[256 * 12 + 12];
    for (int i = threadIdx.x; i < 256 * 12 + 12; i += 256)
        sW[i] = (i < 256 * 12) ? W4[i] : b4[i - 256 * 12];
    __syncthreads();

    const int r = blockIdx.x * 256 + threadIdx.x;
    if (r >= fcount) return;
    const int f = fbase + r;

    float o[12];
#pragma unroll
    for (int n = 0; n < 12; ++n) o[n] = sW[3072 + n];
    const f32x4* ph = (const f32x4*)(H3 + (size_t)r * 256);
    for (int kb = 0; kb < 64; ++kb) {
        f32x4 hv = ph[kb];
#pragma unroll
        for (int kk = 0; kk < 4; ++kk) {
            float val = hv[kk];
            const float* wrow = &sW[(kb * 4 + kk) * 12];
#pragma unroll
            for (int n = 0; n < 12; ++n) o[n] = fmaf(val, wrow[n], o[n]);
        }
    }

    const float M00=o[0], M01=o[1], M02=o[2];
    const float M10=o[3], M11=o[4], M12=o[5];
    const float M20=o[6], M21=o[7], M22=o[8];
    const float t0 =o[9], t1 =o[10], t2 =o[11];

    float a00 = M00*M00 + M10*M10 + M20*M20;
    float a11 = M01*M01 + M11*M11 + M21*M21;
    float a22 = M02*M02 + M12*M12 + M22*M22;
    float a01 = M00*M01 + M10*M11 + M20*M21;
    float a02 = M00*M02 + M10*M12 + M20*M22;
    float a12 = M01*M02 + M11*M12 + M21*M22;

    float v00=1.f, v01=0.f, v02=0.f;
    float v10=0.f, v11=1.f, v12=0.f;
    float v20=0.f, v21=0.f, v22=1.f;
#pragma unroll
    for (int sweep = 0; sweep < 5; ++sweep) {
        JROT(a00, a11, a01, a02, a12, v00, v10, v20, v01, v11, v21);
        JROT(a00, a22, a02, a01, a12, v00, v10, v20, v02, v12, v22);
        JROT(a11, a22, a12, a01, a02, v01, v11, v21, v02, v12, v22);
    }
    float l0 = a00, l1 = a11, l2 = a22;
    if (l0 < l1) SWAP3(l0, l1, v00, v10, v20, v01, v11, v21);
    if (l0 < l2) SWAP3(l0, l2, v00, v10, v20, v02, v12, v22);
    if (l1 < l2) SWAP3(l1, l2, v01, v11, v21, v02, v12, v22);

    float b1x = M00*v00 + M01*v10 + M02*v20;
    float b1y = M10*v00 + M11*v10 + M12*v20;
    float b1z = M20*v00 + M21*v10 + M22*v20;
    float b2x = M00*v01 + M01*v11 + M02*v21;
    float b2y = M10*v01 + M11*v11 + M12*v21;
    float b2z = M20*v01 + M21*v11 + M22*v21;

    float n1 = sqrtf(b1x*b1x + b1y*b1y + b1z*b1z);
    float u1x, u1y, u1z;
    if (n1 > 1e-25f) { float in = 1.0f / n1; u1x = b1x*in; u1y = b1y*in; u1z = b1z*in; }
    else             { u1x = 1.f; u1y = 0.f; u1z = 0.f; }

    float dp  = b2x*u1x + b2y*u1y + b2z*u1z;
    float w2x = b2x - dp*u1x, w2y = b2y - dp*u1y, w2z = b2z - dp*u1z;
    float n2  = sqrtf(w2x*w2x + w2y*w2y + w2z*w2z);
    float u2x, u2y, u2z;
    if (n2 > 1e-25f) { float in = 1.0f / n2; u2x = w2x*in; u2y = w2y*in; u2z = w2z*in; }
    else {
        float ex = (fabsf(u1x) < 0.9f) ? 1.f : 0.f;
        float ey = 1.f - ex;
        float cx = -u1z * ey, cy = u1z * ex, cz = u1x * ey - u1y * ex;
        float cn = rsqrtf(cx*cx + cy*cy + cz*cz);
        u2x = cx * cn; u2y = cy * cn; u2z = cz * cn;
    }
    float u3x = u1y*u2z - u1z*u2y;
    float u3y = u1z*u2x - u1x*u2z;
    float u3z = u1x*u2y - u1y*u2x;

    float dv = v00*(v11*v22 - v12*v21) - v01*(v10*v22 - v12*v20) + v02*(v10*v21 - v11*v20);
    if (dv < 0.f) { v02 = -v02; v12 = -v12; v22 = -v22; }

    float R00 = u1x*v00 + u2x*v01 + u3x*v02;
    float R01 = u1x*v10 + u2x*v11 + u3x*v12;
    float R02 = u1x*v20 + u2x*v21 + u3x*v22;
    float R10 = u1y*v00 + u2y*v01 + u3y*v02;
    float R11 = u1y*v10 + u2y*v11 + u3y*v12;
    float R12 = u1y*v20 + u2y*v21 + u3y*v22;
    float R20 = u1z*v00 + u2z*v01 + u3z*v02;
    float R21 = u1z*v10 + u2z*v11 + u3z*v12;
    float R22 = u1z*v20 + u2z*v21 + u3z*v22;

    float* rp = out_rot + (size_t)f * 9;
    rp[0]=R00; rp[1]=R01; rp[2]=R02;
    rp[3]=R10; rp[4]=R11; rp[5]=R12;
    rp[6]=R20; rp[7]=R21; rp[8]=R22;

    float* tp = out_tp + (size_t)f * 9;
    const int idx[3] = { faces[3*f], faces[3*f+1], faces[3*f+2] };
#pragma unroll
    for (int j = 0; j < 3; ++j) {
        const int vi = idx[j];
        float px = verts[3*vi], py = verts[3*vi+1], pz = verts[3*vi+2];
        float q0 = px*R00 + py*R10 + pz*R20 + t0;
        float q1 = px*R01 + py*R11 + pz*R21 + t1;
        float q2 = px*R02 + py*R12 + pz*R22 + t2;
        tp[j*3+0] = q0; tp[j*3+1] = q1; tp[j*3+2] = q2;
        atomicAdd(&sums[(size_t)vi*3+0], q0);
        atomicAdd(&sums[(size_t)vi*3+1], q1);
        atomicAdd(&sums[(size_t)vi*3+2], q2);
        atomicAdd(&counts[vi], 1.0f);
    }
}

// ---------- kernel: features = sums / clip(counts,1) ----------
__global__ void finalize_kernel(float* __restrict__ feats, const float* __restrict__ counts, int nverts) {
    int v = blockIdx.x * 256 + threadIdx.x;
    if (v >= nverts) return;
    float c = fmaxf(counts[v], 1.0f);
    feats[v*3+0] = feats[v*3+0] / c;
    feats[v*3+1] = feats[v*3+1] / c;
    feats[v*3+2] = feats[v*3+2] / c;
}

// ---------- host ----------
extern "C" void kernel_launch(void* const* d_in, const int* in_sizes, int n_in,
                              void* d_out, int out_size, void* d_ws, size_t ws_size,
                              hipStream_t stream) {
    const float* x     = (const float*)d_in[0];
    const float* verts = (const float*)d_in[1];
    const int*   faces = (const int*)d_in[2];
    const float* W1 = (const float*)d_in[3];
    const float* b1 = (const float*)d_in[4];
    const float* W2 = (const float*)d_in[5];
    const float* b2 = (const float*)d_in[6];
    const float* W3 = (const float*)d_in[7];
    const float* b3 = (const float*)d_in[8];
    const float* W4 = (const float*)d_in[9];
    const float* b4 = (const float*)d_in[10];

    const int nverts = in_sizes[1] / 3;
    const int nfaces = in_sizes[2] / 3;

    float* out_feats = (float*)d_out;
    float* out_tp    = out_feats + (size_t)nverts * 3;
    float* out_rot   = out_tp + (size_t)nfaces * 9;

    char* ws = (char*)d_ws;
    size_t cur = 0;
    auto carve = [&](size_t bytes) -> void* {
        void* p = ws + cur;
        cur += (bytes + 255) & ~(size_t)255;
        return p;
    };
    unsigned short* w1h = (unsigned short*)carve(512 * 512 * 2);
    unsigned short* w1l = (unsigned short*)carve(512 * 512 * 2);
    unsigned short* w2h = (unsigned short*)carve(512 * 512 * 2);
    unsigned short* w2l = (unsigned short*)carve(512 * 512 * 2);
    unsigned short* w3h = (unsigned short*)carve(256 * 512 * 2);
    unsigned short* w3l = (unsigned short*)carve(256 * 512 * 2);
    float* counts = (float*)carve((size_t)nverts * 4);

    const long MV = ((long)nverts + 127) & ~127L;   // padded vertex rows
    const long MF = ((long)nfaces + 127) & ~127L;   // padded face rows
    const size_t szY   = (size_t)MV * 512 * 4;      // y fp32
    const size_t szH2w = (size_t)MF * 512 * 2;      // one 512-wide bf16 plane
    const size_t szH3f = (size_t)MF * 256 * 4;      // h3 fp32

    const size_t sR1 = (szY > szH3f) ? szY : szH3f;        // y -> h3 (fp32)
    const size_t sR2 = szH2w;                              // h2h
    const size_t sR3 = szH2w;                              // h2l
    const size_t need = cur + sR1 + sR2 + sR3 + 4 * 256;

    prep_weights<<<(655360 + 255) / 256, 256, 0, stream>>>(W1, W2, W3, w1h, w1l, w2h, w2l, w3h, w3l,
                                                           out_feats, counts, nverts);

    if (ws_size >= need) {
        // ---- main path: vertex-GEMM linearity trick; gather fused into L2 ----
        char* R1 = (char*)carve(sR1);
        char* R2 = (char*)carve(sR2);
        char* R3 = (char*)carve(sR3);
        float*          y   = (float*)R1;
        float*          h3  = (float*)R1;      // aliases y (y dead after L2)
        unsigned short* h2h = (unsigned short*)R2;
        unsigned short* h2l = (unsigned short*)R3;

        // L1 on vertices: y = x @ W1 (fused fp32->split staging; no bias/relu yet)
        gemm_l1<<<(int)(MV / 128) * 4, 256, 0, stream>>>(x, w1h, w1l, y, 512, 512, 4, nverts);

        // L2 with fused gather (48 KB LDS, 3 blocks/CU via LDS limit)
        gemm_l2g48<<<(int)(MF / 128) * 4, 256, 0, stream>>>(y, faces, b1, w2h, w2l, b2,
                                                            h2h, h2l, 512, 512, 4, nfaces);

        // L3: h3 = relu(h2 @ W3 + b3), fp32 out (h3 aliases dead y)
        gemm_pipe<2><<<(int)(MF / 128) * 2, 256, 0, stream>>>(h2h, h2l, w3h, w3l, b3, h3, nullptr, 256, 512, 2);

        face_kernel<<<(nfaces + 255) / 256, 256, 0, stream>>>(h3, W4, b4, verts, faces,
                                                              out_tp, out_rot, out_feats, counts,
                                                              0, nfaces);
    } else {
        // ---- fallback: chunked face-row pipeline ----
        long mpad = MF;
        size_t avail = (ws_size > cur) ? (ws_size - cur) : 0;
        long chp = (long)(avail / 4096);
        chp &= ~127L;
        if (chp > mpad) chp = mpad;
        if (chp < 128) chp = 128;
        unsigned short* bAh = (unsigned short*)carve((size_t)chp * 512 * 2);
        unsigned short* bAl = (unsigned short*)carve((size_t)chp * 512 * 2);
        unsigned short* bBh = (unsigned short*)carve((size_t)chp * 512 * 2);
        unsigned short* bBl = (unsigned short*)carve((size_t)chp * 512 * 2);

        for (long base = 0; base < nfaces; base += chp) {
            long rem = (long)nfaces - base;
            int cnt = (int)((rem < chp) ? rem : chp);
            int mc  = (cnt + 127) & ~127;

            gather_mean<<<mc / 2, 256, 0, stream>>>(x, faces, bAh, bAl, (int)base, cnt, mc);
            gemm_pipe<0><<<(mc / 128) * 4, 256, 0, stream>>>(bAh, bAl, w1h, w1l, b1, bBh, bBl, 512, 512, 4);
            gemm_pipe<0><<<(mc / 128) * 4, 256, 0, stream>>>(bBh, bBl, w2h, w2l, b2, bAh, bAl, 512, 512, 4);
            gemm_pipe<2><<<(mc / 128) * 2, 256, 0, stream>>>(bAh, bAl, w3h, w3l, b3, (float*)bBh, nullptr, 256, 512, 2);
            face_kernel<<<(cnt + 255) / 256, 256, 0, stream>>>((float*)bBh, W4, b4, verts, faces,
                                                               out_tp, out_rot, out_feats, counts,
                                                               (int)base, cnt);
        }
    }

    finalize_kernel<<<(nverts + 255) / 256, 256, 0, stream>>>(out_feats, counts, nverts);
}